// Round 16
// baseline (208.094 us; speedup 1.0000x reference)
//
#include <hip/hip_runtime.h>
#include <stdint.h>

// Problem constants
#define T_DIM 2048
#define B_DIM 4
#define D_DIM 1024
#define H_NUM 16
#define HD 64
#define MROWS (T_DIM * B_DIM)     // 8192 flattened (t*B+b) rows
#define QKV_N (3 * D_DIM)         // 3072
// softmax in log2 domain: Q pre-scaled by 1/sqrt(64)*log2(e) in the QKV GEMM
#define ATT_C 0.18033688011112042f

typedef unsigned short u16;
typedef __bf16 bf16x8 __attribute__((ext_vector_type(8)));
typedef float f32x4 __attribute__((ext_vector_type(4)));
typedef float f32x16 __attribute__((ext_vector_type(16)));
typedef u16 u16x4 __attribute__((ext_vector_type(4)));
typedef u16 u16x8 __attribute__((ext_vector_type(8)));

__device__ __forceinline__ u16 f2bf(float f) {
  union { float f; unsigned u; } v; v.f = f;
  unsigned r = v.u + 0x7fffu + ((v.u >> 16) & 1u);
  return (u16)(r >> 16);
}

__device__ __forceinline__ void async_copy16(void* lds, const void* g) {
  __builtin_amdgcn_global_load_lds((__attribute__((address_space(1))) void*)(g),
                                   (__attribute__((address_space(3))) void*)(lds),
                                   16, 0, 0);
}

// ---------------- fused fp32 -> bf16 cast (3 inputs, contiguous dst) -------
__global__ __launch_bounds__(256) void cast3_f32_bf16(
    const float* __restrict__ s0, const float* __restrict__ s1,
    const float* __restrict__ s2, u16* __restrict__ dst,
    int n0, int n01, int ntot4) {
  int i = blockIdx.x * 256 + threadIdx.x;
  if (i >= ntot4) return;
  int e = i * 4;
  const float* s; int off;
  if (e < n0) { s = s0; off = 0; }
  else if (e < n01) { s = s1; off = n0; }
  else { s = s2; off = n01; }
  float4 v = *reinterpret_cast<const float4*>(s + (e - off));
  u16x4 o = {f2bf(v.x), f2bf(v.y), f2bf(v.z), f2bf(v.w)};
  *reinterpret_cast<u16x4*>(dst + e) = o;
}

// ---------------- 128^2 m97 GEMM (kept for out-projection) ----------------
template <int OUT_F32_BIAS>
__global__ __launch_bounds__(256) void gemm_bt(
    const u16* __restrict__ A, const u16* __restrict__ Bm,
    u16* __restrict__ Cb, float* __restrict__ Cf, const float* __restrict__ bias,
    int M, int N, int K) {
  __shared__ __attribute__((aligned(16))) u16 As[128 * 64];
  __shared__ __attribute__((aligned(16))) u16 Bs[128 * 64];

  const int tid = threadIdx.x;
  const int lane = tid & 63, wid = tid >> 6;
  const int l15 = lane & 15, lg = lane >> 4;
  const int wr = wid >> 1, wc = wid & 1;
  const int m0 = blockIdx.y * 128, n0 = blockIdx.x * 128;

  f32x4 acc[4][4];
#pragma unroll
  for (int i = 0; i < 4; i++)
#pragma unroll
    for (int j = 0; j < 4; j++) acc[i][j] = (f32x4){0.f, 0.f, 0.f, 0.f};

  const int srow = tid >> 3;
  const int scol = (tid & 7) * 8;
  const u16* gA = A + (size_t)(m0 + srow) * K + scol;
  const u16* gB = Bm + (size_t)(n0 + srow) * K + scol;
  u16* lA = As + tid * 8;
  u16* lB = Bs + tid * 8;

  const int KT = K >> 6;
  for (int kt = 0; kt < KT; ++kt) {
    const int kofs = kt * 64;
#pragma unroll
    for (int p = 0; p < 4; ++p) {
      async_copy16(lA + p * 256 * 8, gA + (size_t)(p * 32) * K + kofs);
      async_copy16(lB + p * 256 * 8, gB + (size_t)(p * 32) * K + kofs);
    }
    __syncthreads();
#pragma unroll
    for (int kk = 0; kk < 2; ++kk) {
      bf16x8 af[4], bfr[4];
#pragma unroll
      for (int mt = 0; mt < 4; ++mt)
        af[mt] = *reinterpret_cast<const bf16x8*>(
            &As[(wr * 64 + mt * 16 + l15) * 64 + kk * 32 + lg * 8]);
#pragma unroll
      for (int nt = 0; nt < 4; ++nt)
        bfr[nt] = *reinterpret_cast<const bf16x8*>(
            &Bs[(wc * 64 + nt * 16 + l15) * 64 + kk * 32 + lg * 8]);
#pragma unroll
      for (int mt = 0; mt < 4; ++mt)
#pragma unroll
        for (int nt = 0; nt < 4; ++nt)
          acc[mt][nt] = __builtin_amdgcn_mfma_f32_16x16x32_bf16(
              af[mt], bfr[nt], acc[mt][nt], 0, 0, 0);
    }
    __syncthreads();
  }

#pragma unroll
  for (int mt = 0; mt < 4; ++mt) {
#pragma unroll
    for (int r = 0; r < 4; ++r) {
      const int row = m0 + wr * 64 + mt * 16 + lg * 4 + r;
#pragma unroll
      for (int nt = 0; nt < 4; ++nt) {
        const int col = n0 + wc * 64 + nt * 16 + l15;
        float v = acc[mt][nt][r];
        if (OUT_F32_BIAS) {
          Cf[(size_t)row * N + col] = v + bias[col];
        } else {
          Cb[(size_t)row * N + col] = f2bf(v);
        }
      }
    }
  }
}

// ---------------- 256^2 8-phase counted-vmcnt GEMM (QKV, unchanged) --------
__global__ __launch_bounds__(512, 1) void gemm_bt8_qkv(
    const u16* __restrict__ A, const u16* __restrict__ Bm,
    u16* __restrict__ Cb, int M, int N, int K) {
  extern __shared__ u16 sm[];

  const int tid = threadIdx.x;
  const int lane = tid & 63, wid = tid >> 6;
  const int wr = wid >> 2, wc = wid & 3;
  const int l15 = lane & 15, lg = lane >> 4;
  const int xr = ((l15 >> 2) & 1) << 4;

  const int nwg = gridDim.x * gridDim.y;
  const int lin = blockIdx.y * gridDim.x + blockIdx.x;
  const int swz = (lin & 7) * (nwg >> 3) + (lin >> 3);
  const int bx = swz % gridDim.x, by = swz / gridDim.x;
  const int m0 = by * 256, n0 = bx * 256;

  const int srow = tid >> 3;
  const int kxs = ((tid & 7) * 8) ^ (((tid >> 5) & 1) << 4);
  const u16* gA = A + (size_t)(m0 + srow) * K + kxs;
  const u16* gB = Bm + (size_t)(n0 + srow) * K + kxs;

#define STG(op_, h_, tk_, c_)                                                   \
  {                                                                             \
    const u16* g_ = ((op_) ? gB : gA) + (size_t)((h_) * 128) * K + (size_t)(tk_) * 64; \
    u16* d_ = sm + (c_) * 32768 + (op_) * 16384 + (h_) * 8192 + tid * 8;        \
    async_copy16(d_, g_);                                                       \
    async_copy16(d_ + 4096, g_ + (size_t)64 * K);                               \
  }
#define LDA_(mt_, kk_, c_)                                                      \
  (*reinterpret_cast<const bf16x8*>(sm + (c_) * 32768 + wr * 8192 +             \
      ((mt_) * 16 + l15) * 64 + (((kk_) * 32 + lg * 8) ^ xr)))
#define LDB_(nt_, kk_, c_)                                                      \
  (*reinterpret_cast<const bf16x8*>(sm + (c_) * 32768 + 16384 + (wc >> 1) * 8192 + \
      ((wc & 1) * 64 + (nt_) * 16 + l15) * 64 + (((kk_) * 32 + lg * 8) ^ xr)))

  f32x4 acc[8][4];
#pragma unroll
  for (int i = 0; i < 8; i++)
#pragma unroll
    for (int j = 0; j < 4; j++) acc[i][j] = (f32x4){0.f, 0.f, 0.f, 0.f};

  const int NT = K >> 6;

  STG(0, 0, 0, 0) STG(0, 1, 0, 0) STG(1, 0, 0, 0) STG(1, 1, 0, 0)
  STG(0, 0, 1, 1) STG(0, 1, 1, 1)
  asm volatile("s_waitcnt vmcnt(4)" ::: "memory");
  __builtin_amdgcn_sched_barrier(0);
  __builtin_amdgcn_s_barrier();

  for (int t = 0; t < NT; ++t) {
    const int c = t & 1;
    bf16x8 a03[4][2], a47[4][2], b01[2][2], b23[2][2];
#pragma unroll
    for (int mt = 0; mt < 4; ++mt) {
      a03[mt][0] = LDA_(mt, 0, c);
      a03[mt][1] = LDA_(mt, 1, c);
    }
#pragma unroll
    for (int nt = 0; nt < 2; ++nt) {
      b01[nt][0] = LDB_(nt, 0, c);
      b01[nt][1] = LDB_(nt, 1, c);
    }
    if (t + 1 < NT) STG(1, 0, t + 1, c ^ 1)
    __builtin_amdgcn_s_barrier();
    asm volatile("s_waitcnt lgkmcnt(0)" ::: "memory");
    __builtin_amdgcn_sched_barrier(0);
    __builtin_amdgcn_s_setprio(1);
#pragma unroll
    for (int mt = 0; mt < 4; ++mt)
#pragma unroll
      for (int nt = 0; nt < 2; ++nt)
#pragma unroll
        for (int kk = 0; kk < 2; ++kk)
          acc[mt][nt] = __builtin_amdgcn_mfma_f32_16x16x32_bf16(
              a03[mt][kk], b01[nt][kk], acc[mt][nt], 0, 0, 0);
    __builtin_amdgcn_s_setprio(0);
    __builtin_amdgcn_s_barrier();
#pragma unroll
    for (int mt = 0; mt < 4; ++mt) {
      a47[mt][0] = LDA_(mt + 4, 0, c);
      a47[mt][1] = LDA_(mt + 4, 1, c);
    }
    if (t + 1 < NT) STG(1, 1, t + 1, c ^ 1)
    __builtin_amdgcn_s_barrier();
    asm volatile("s_waitcnt lgkmcnt(0)" ::: "memory");
    __builtin_amdgcn_sched_barrier(0);
    __builtin_amdgcn_s_setprio(1);
#pragma unroll
    for (int mt = 0; mt < 4; ++mt)
#pragma unroll
      for (int nt = 0; nt < 2; ++nt)
#pragma unroll
        for (int kk = 0; kk < 2; ++kk)
          acc[mt + 4][nt] = __builtin_amdgcn_mfma_f32_16x16x32_bf16(
              a47[mt][kk], b01[nt][kk], acc[mt + 4][nt], 0, 0, 0);
    __builtin_amdgcn_s_setprio(0);
    __builtin_amdgcn_s_barrier();
#pragma unroll
    for (int nt = 0; nt < 2; ++nt) {
      b23[nt][0] = LDB_(nt + 2, 0, c);
      b23[nt][1] = LDB_(nt + 2, 1, c);
    }
    if (t + 2 < NT) STG(0, 0, t + 2, c)
    __builtin_amdgcn_s_barrier();
    asm volatile("s_waitcnt lgkmcnt(0)" ::: "memory");
    __builtin_amdgcn_sched_barrier(0);
    __builtin_amdgcn_s_setprio(1);
#pragma unroll
    for (int mt = 0; mt < 4; ++mt)
#pragma unroll
      for (int nt = 0; nt < 2; ++nt)
#pragma unroll
        for (int kk = 0; kk < 2; ++kk)
          acc[mt][nt + 2] = __builtin_amdgcn_mfma_f32_16x16x32_bf16(
              a03[mt][kk], b23[nt][kk], acc[mt][nt + 2], 0, 0, 0);
    __builtin_amdgcn_s_setprio(0);
    __builtin_amdgcn_s_barrier();
    if (t + 2 < NT) STG(0, 1, t + 2, c)
    __builtin_amdgcn_s_barrier();
    __builtin_amdgcn_s_setprio(1);
#pragma unroll
    for (int mt = 0; mt < 4; ++mt)
#pragma unroll
      for (int nt = 0; nt < 2; ++nt)
#pragma unroll
        for (int kk = 0; kk < 2; ++kk)
          acc[mt + 4][nt + 2] = __builtin_amdgcn_mfma_f32_16x16x32_bf16(
              a47[mt][kk], b23[nt][kk], acc[mt + 4][nt + 2], 0, 0, 0);
    __builtin_amdgcn_s_setprio(0);
    if (t + 1 < NT) {
      if (t + 2 < NT) {
        asm volatile("s_waitcnt vmcnt(4)" ::: "memory");
      } else {
        asm volatile("s_waitcnt vmcnt(0)" ::: "memory");
      }
      __builtin_amdgcn_sched_barrier(0);
    }
    __builtin_amdgcn_s_barrier();
  }

  const float qsc = (n0 < D_DIM) ? ATT_C : 1.0f;
#pragma unroll
  for (int mt = 0; mt < 8; ++mt) {
#pragma unroll
    for (int r = 0; r < 4; ++r) {
      const int row = m0 + wr * 128 + mt * 16 + lg * 4 + r;
#pragma unroll
      for (int nt = 0; nt < 4; ++nt) {
        const int col = n0 + wc * 64 + nt * 16 + l15;
        Cb[(size_t)row * N + col] = f2bf(acc[mt][nt][r] * qsc);
      }
    }
  }
#undef STG
#undef LDA_
#undef LDB_
}

// ---------------- causal flash attention: 8-wave, 2 kv-groups, KVBLK=64 ----
// R14 structure with per-group KVBLK 128->64: per-group LDS = 20480 B,
// block total 40960 B -> 2 blocks/CU fit WITH slack (R14's 81920B x2 =
// exactly 160K failed vs driver reserve). VGPR 112 <= 128 -> 4 waves/SIMD.
// Group g handles 64-row kv tiles kt == g (mod 2); fixed-shift partials
// merge as plain sums at the end; group 0 writes.
#define VF_STRIDE 24
#define VF_FRAG (32 * VF_STRIDE)
#define KS_U16 4096                       // 64x64 u16
#define GRP_U16 (KS_U16 + 8 * VF_FRAG)    // 10240 u16 = 20480 B per group

__device__ __forceinline__ void process32(
    const bf16x8 (&qf)[4], f32x16 (&o)[2], f32x16& lacc,
    int q0w, int kv0, int l31, int hi, bool needMask, const bf16x8 onesf,
    const u16* __restrict__ Ks, const u16* __restrict__ Vf) {
  f32x16 s[2];
#pragma unroll
  for (int kb = 0; kb < 2; ++kb)
#pragma unroll
    for (int r = 0; r < 16; ++r) s[kb][r] = 0.f;

  __builtin_amdgcn_s_setprio(1);
#pragma unroll
  for (int kb = 0; kb < 2; ++kb) {
#pragma unroll
    for (int ks = 0; ks < 4; ++ks) {
      const int row = kb * 32 + l31;
      bf16x8 kf = *reinterpret_cast<const bf16x8*>(
          &Ks[row * 64 + ((((ks << 1) | hi)) ^ (l31 & 7)) * 8]);
      s[kb] = __builtin_amdgcn_mfma_f32_32x32x16_bf16(kf, qf[ks], s[kb], 0, 0, 0);
    }
  }
  __builtin_amdgcn_s_setprio(0);

  if (needMask) {
    const int q = q0w + l31;
#pragma unroll
    for (int kb = 0; kb < 2; ++kb)
#pragma unroll
      for (int r = 0; r < 16; ++r) {
        const int kv = kv0 + kb * 32 + (r & 3) + ((r >> 2) << 3) + (hi << 2);
        if (kv > q) s[kb][r] = -1e30f;
      }
  }
#pragma unroll
  for (int kb = 0; kb < 2; ++kb)
#pragma unroll
    for (int r = 0; r < 16; ++r)
      s[kb][r] = __builtin_amdgcn_exp2f(s[kb][r]);

  union Frag { unsigned u[4]; bf16x8 v; };
  Frag pf[4];
#pragma unroll
  for (int kb = 0; kb < 2; ++kb)
#pragma unroll
    for (int g = 0; g < 2; ++g) {
#pragma unroll
      for (int t2 = 0; t2 < 2; ++t2) {
        unsigned x, y;
        asm("v_cvt_pk_bf16_f32 %0, %1, %2"
            : "=v"(x) : "v"(s[kb][g * 8 + t2 * 2]), "v"(s[kb][g * 8 + t2 * 2 + 1]));
        asm("v_cvt_pk_bf16_f32 %0, %1, %2"
            : "=v"(y) : "v"(s[kb][g * 8 + t2 * 2 + 4]), "v"(s[kb][g * 8 + t2 * 2 + 5]));
        asm("v_permlane32_swap_b32 %0, %1" : "+v"(x), "+v"(y));
        pf[kb * 2 + g].u[t2] = x;
        pf[kb * 2 + g].u[t2 + 2] = y;
      }
    }

  __builtin_amdgcn_s_setprio(1);
#pragma unroll
  for (int ks = 0; ks < 4; ++ks) {
    lacc = __builtin_amdgcn_mfma_f32_32x32x16_bf16(onesf, pf[ks].v, lacc, 0, 0, 0);
#pragma unroll
    for (int db = 0; db < 2; ++db) {
      bf16x8 vf = *reinterpret_cast<const bf16x8*>(
          &Vf[(ks * 2 + db) * VF_FRAG + l31 * VF_STRIDE + hi * 8]);
      o[db] = __builtin_amdgcn_mfma_f32_32x32x16_bf16(vf, pf[ks].v, o[db], 0, 0, 0);
    }
  }
  __builtin_amdgcn_s_setprio(0);
}

__global__ __launch_bounds__(512, 2) void attn_kernel(
    const u16* __restrict__ qkv, u16* __restrict__ aout) {
  extern __shared__ __attribute__((aligned(16))) u16 smA[];  // 2 x GRP_U16

  const int tid = threadIdx.x;
  const int lane = tid & 63, w = tid >> 6;        // 0..7
  const int g = w >> 2, wl = w & 3;               // kv-group, wave-in-group
  const int ltid = tid & 255;
  const int l31 = lane & 31, hi = lane >> 5;

  // XCD swizzle: 512 blocks -> 64 contiguous per XCD
  const int nwg = gridDim.x * gridDim.y;          // 512
  const int lin = blockIdx.y * gridDim.x + blockIdx.x;
  const int swz = (lin & 7) * (nwg >> 3) + (lin >> 3);
  const int px = swz % gridDim.x;                 // pair index 0..7
  const int bh = swz / gridDim.x;
  const int b = bh >> 4, h = bh & 15;
  const int qtA = px, qtB = 15 - px;              // qtA < qtB
  const int q0A = qtA * 128 + wl * 32, q0B = qtB * 128 + wl * 32;

  u16* Ks = smA + g * GRP_U16;
  u16* Vf = Ks + KS_U16;

  // Q fragments (same q rows for both groups)
  bf16x8 qfA[4], qfB[4];
  {
    const u16* pA = qkv + ((size_t)(q0A + l31) * B_DIM + b) * QKV_N + h * HD + hi * 8;
    const u16* pB = qkv + ((size_t)(q0B + l31) * B_DIM + b) * QKV_N + h * HD + hi * 8;
#pragma unroll
    for (int ks = 0; ks < 4; ++ks) {
      qfA[ks] = *reinterpret_cast<const bf16x8*>(pA + ks * 16);
      qfB[ks] = *reinterpret_cast<const bf16x8*>(pB + ks * 16);
    }
  }

  bf16x8 onesf;
  {
    union { u16 u[8]; bf16x8 v; } ou;
#pragma unroll
    for (int i = 0; i < 8; ++i) ou.u[i] = 0x3F80;
    onesf = ou.v;
  }

  f32x16 oA[2], oB[2], laccA, laccB;
#pragma unroll
  for (int r = 0; r < 16; ++r) { laccA[r] = 0.f; laccB[r] = 0.f; }
#pragma unroll
  for (int db = 0; db < 2; ++db)
#pragma unroll
    for (int r = 0; r < 16; ++r) { oA[db][r] = 0.f; oB[db][r] = 0.f; }

  const int srow = ltid >> 3;                // 0..31 (within group)
  const int scol = (ltid & 7) * 8;
  const int csw = (ltid & 7) ^ (srow & 7);   // pre-swizzled K source chunk

  const int ntiles = 2 * qtB + 2;            // 64-row kv tiles
  const int iters = (ntiles + 1) >> 1;       // = qtB + 1
  for (int it = 0; it < iters; ++it) {
    const int kt = 2 * it + g;               // interleaved split across groups
    const bool active = kt < ntiles;
    const int kv0 = kt * 64;
    if (active) {
      // stage K 64x64 (2 passes of 32 rows; swizzled source, linear dest)
#pragma unroll
      for (int p = 0; p < 2; ++p) {
        const u16* gK = qkv + ((size_t)(kv0 + p * 32 + srow) * B_DIM + b) * QKV_N +
                        D_DIM + h * HD + csw * 8;
        async_copy16(Ks + ltid * 8 + p * 2048, gK);
      }
      // stage V -> padded V^T fragment layout
      u16x8 vv[2];
#pragma unroll
      for (int p = 0; p < 2; ++p) {
        const u16* gV = qkv + ((size_t)(kv0 + p * 32 + srow) * B_DIM + b) * QKV_N +
                        2 * D_DIM + h * HD + scol;
        vv[p] = *reinterpret_cast<const u16x8*>(gV);
      }
#pragma unroll
      for (int p = 0; p < 2; ++p) {
        const int kvl = p * 32 + srow;       // 0..63
        const int fb = (kvl >> 4) * 2;
        const int e16 = kvl & 15;
#pragma unroll
        for (int jj = 0; jj < 8; ++jj) {
          const int j = (jj + srow) & 7;
          const int d = scol + j;
          Vf[(fb + (d >> 5)) * VF_FRAG + (d & 31) * VF_STRIDE + e16] = vv[p][j];
        }
      }
    }
    __syncthreads();
    if (active) {
      if (kv0 <= q0A + 31)
        process32(qfA, oA, laccA, q0A, kv0, l31, hi, kv0 + 63 > q0A, onesf, Ks, Vf);
      if (kv0 <= q0B + 31)
        process32(qfB, oB, laccB, q0B, kv0, l31, hi, kv0 + 63 > q0B, onesf, Ks, Vf);
    }
    __syncthreads();
  }

  // ---- merge group1 partials into group0 via LDS (fixed-shift: plain sums)
  float* mb = (float*)smA;                   // 16KB needed <= 40960B
#define MPASS(vec_)                                                            \
  __syncthreads();                                                             \
  if (g == 1) {                                                                \
    _Pragma("unroll") for (int r = 0; r < 16; ++r)                             \
        mb[r * 256 + wl * 64 + lane] = vec_[r];                                \
  }                                                                            \
  __syncthreads();                                                             \
  if (g == 0) {                                                                \
    _Pragma("unroll") for (int r = 0; r < 16; ++r)                             \
        vec_[r] += mb[r * 256 + wl * 64 + lane];                               \
  }
  MPASS(oA[0]) MPASS(oA[1]) MPASS(oB[0]) MPASS(oB[1])
  __syncthreads();
  if (g == 1) {
    mb[wl * 64 + lane] = laccA[0];
    mb[256 + wl * 64 + lane] = laccB[0];
  }
  __syncthreads();
  if (g == 0) {
    laccA[0] += mb[wl * 64 + lane];
    laccB[0] += mb[256 + wl * 64 + lane];
  }
#undef MPASS

  // epilogue (group 0 only)
  if (g == 0) {
#pragma unroll
    for (int t = 0; t < 2; ++t) {
      const float inv = 1.0f / (t == 0 ? laccA[0] : laccB[0]);
      const int q0w = t == 0 ? q0A : q0B;
      f32x16* o = t == 0 ? oA : oB;
      u16* orow = aout + ((size_t)(q0w + l31) * B_DIM + b) * D_DIM + h * HD;
#pragma unroll
      for (int db = 0; db < 2; ++db)
#pragma unroll
        for (int rq = 0; rq < 4; ++rq) {
          u16x4 o4;
#pragma unroll
          for (int e = 0; e < 4; ++e) o4[e] = f2bf(o[db][rq * 4 + e] * inv);
          *reinterpret_cast<u16x4*>(orow + db * 32 + rq * 8 + hi * 4) = o4;
        }
    }
  }
}

// ---------------- launch ----------------
extern "C" void kernel_launch(void* const* d_in, const int* in_sizes, int n_in,
                              void* d_out, int out_size, void* d_ws, size_t ws_size,
                              hipStream_t stream) {
  (void)in_sizes; (void)n_in; (void)out_size; (void)ws_size;
  const float* x = (const float*)d_in[0];
  const float* Wqkv = (const float*)d_in[1];
  const float* Wout = (const float*)d_in[2];
  const float* bout = (const float*)d_in[3];
  float* out = (float*)d_out;

  u16* xb = (u16*)d_ws;                               // [8192][1024]
  u16* wqkvb = xb + (size_t)MROWS * D_DIM;            // [3072][1024]
  u16* woutb = wqkvb + (size_t)QKV_N * D_DIM;         // [1024][1024]
  u16* qkv = woutb + (size_t)D_DIM * D_DIM;           // [8192][3072]
  u16* aout = qkv + (size_t)MROWS * QKV_N;            // [8192][1024]

  {
    const int n0 = MROWS * D_DIM;
    const int n01 = n0 + QKV_N * D_DIM;
    const int ntot = n01 + D_DIM * D_DIM;
    const int n4 = ntot / 4;
    cast3_f32_bf16<<<(n4 + 255) / 256, 256, 0, stream>>>(
        x, Wqkv, Wout, xb, n0, n01, n4);
  }

  hipFuncSetAttribute((const void*)gemm_bt8_qkv,
                      hipFuncAttributeMaxDynamicSharedMemorySize, 131072);
  gemm_bt8_qkv<<<dim3(QKV_N / 256, MROWS / 256), 512, 131072, stream>>>(
      xb, wqkvb, qkv, MROWS, QKV_N, D_DIM);

  hipFuncSetAttribute((const void*)attn_kernel,
                      hipFuncAttributeMaxDynamicSharedMemorySize, 2 * GRP_U16 * 2);
  attn_kernel<<<dim3(8, B_DIM * H_NUM), 512, 2 * GRP_U16 * 2, stream>>>(qkv, aout);

  gemm_bt<1><<<dim3(D_DIM / 128, MROWS / 128), 256, 0, stream>>>(
      aout, woutb, nullptr, out, bout, MROWS, D_DIM, D_DIM);
}

// Round 17
// 189.242 us; speedup vs baseline: 1.0996x; 1.0996x over previous
//
#include <hip/hip_runtime.h>
#include <stdint.h>

// Problem constants
#define T_DIM 2048
#define B_DIM 4
#define D_DIM 1024
#define H_NUM 16
#define HD 64
#define MROWS (T_DIM * B_DIM)     // 8192 flattened (t*B+b) rows
#define QKV_N (3 * D_DIM)         // 3072
// softmax in log2 domain: Q pre-scaled by 1/sqrt(64)*log2(e) in the QKV GEMM
#define ATT_C 0.18033688011112042f

typedef unsigned short u16;
typedef __bf16 bf16x8 __attribute__((ext_vector_type(8)));
typedef float f32x4 __attribute__((ext_vector_type(4)));
typedef float f32x16 __attribute__((ext_vector_type(16)));
typedef u16 u16x4 __attribute__((ext_vector_type(4)));
typedef u16 u16x8 __attribute__((ext_vector_type(8)));

__device__ __forceinline__ u16 f2bf(float f) {
  union { float f; unsigned u; } v; v.f = f;
  unsigned r = v.u + 0x7fffu + ((v.u >> 16) & 1u);
  return (u16)(r >> 16);
}

__device__ __forceinline__ void async_copy16(void* lds, const void* g) {
  __builtin_amdgcn_global_load_lds((__attribute__((address_space(1))) void*)(g),
                                   (__attribute__((address_space(3))) void*)(lds),
                                   16, 0, 0);
}

// ---------------- fused fp32 -> bf16 cast (3 inputs, contiguous dst) -------
__global__ __launch_bounds__(256) void cast3_f32_bf16(
    const float* __restrict__ s0, const float* __restrict__ s1,
    const float* __restrict__ s2, u16* __restrict__ dst,
    int n0, int n01, int ntot4) {
  int i = blockIdx.x * 256 + threadIdx.x;
  if (i >= ntot4) return;
  int e = i * 4;
  const float* s; int off;
  if (e < n0) { s = s0; off = 0; }
  else if (e < n01) { s = s1; off = n0; }
  else { s = s2; off = n01; }
  float4 v = *reinterpret_cast<const float4*>(s + (e - off));
  u16x4 o = {f2bf(v.x), f2bf(v.y), f2bf(v.z), f2bf(v.w)};
  *reinterpret_cast<u16x4*>(dst + e) = o;
}

// ---------------- 128^2 m97 GEMM (kept for out-projection) ----------------
template <int OUT_F32_BIAS>
__global__ __launch_bounds__(256) void gemm_bt(
    const u16* __restrict__ A, const u16* __restrict__ Bm,
    u16* __restrict__ Cb, float* __restrict__ Cf, const float* __restrict__ bias,
    int M, int N, int K) {
  __shared__ __attribute__((aligned(16))) u16 As[128 * 64];
  __shared__ __attribute__((aligned(16))) u16 Bs[128 * 64];

  const int tid = threadIdx.x;
  const int lane = tid & 63, wid = tid >> 6;
  const int l15 = lane & 15, lg = lane >> 4;
  const int wr = wid >> 1, wc = wid & 1;
  const int m0 = blockIdx.y * 128, n0 = blockIdx.x * 128;

  f32x4 acc[4][4];
#pragma unroll
  for (int i = 0; i < 4; i++)
#pragma unroll
    for (int j = 0; j < 4; j++) acc[i][j] = (f32x4){0.f, 0.f, 0.f, 0.f};

  const int srow = tid >> 3;
  const int scol = (tid & 7) * 8;
  const u16* gA = A + (size_t)(m0 + srow) * K + scol;
  const u16* gB = Bm + (size_t)(n0 + srow) * K + scol;
  u16* lA = As + tid * 8;
  u16* lB = Bs + tid * 8;

  const int KT = K >> 6;
  for (int kt = 0; kt < KT; ++kt) {
    const int kofs = kt * 64;
#pragma unroll
    for (int p = 0; p < 4; ++p) {
      async_copy16(lA + p * 256 * 8, gA + (size_t)(p * 32) * K + kofs);
      async_copy16(lB + p * 256 * 8, gB + (size_t)(p * 32) * K + kofs);
    }
    __syncthreads();
#pragma unroll
    for (int kk = 0; kk < 2; ++kk) {
      bf16x8 af[4], bfr[4];
#pragma unroll
      for (int mt = 0; mt < 4; ++mt)
        af[mt] = *reinterpret_cast<const bf16x8*>(
            &As[(wr * 64 + mt * 16 + l15) * 64 + kk * 32 + lg * 8]);
#pragma unroll
      for (int nt = 0; nt < 4; ++nt)
        bfr[nt] = *reinterpret_cast<const bf16x8*>(
            &Bs[(wc * 64 + nt * 16 + l15) * 64 + kk * 32 + lg * 8]);
#pragma unroll
      for (int mt = 0; mt < 4; ++mt)
#pragma unroll
        for (int nt = 0; nt < 4; ++nt)
          acc[mt][nt] = __builtin_amdgcn_mfma_f32_16x16x32_bf16(
              af[mt], bfr[nt], acc[mt][nt], 0, 0, 0);
    }
    __syncthreads();
  }

#pragma unroll
  for (int mt = 0; mt < 4; ++mt) {
#pragma unroll
    for (int r = 0; r < 4; ++r) {
      const int row = m0 + wr * 64 + mt * 16 + lg * 4 + r;
#pragma unroll
      for (int nt = 0; nt < 4; ++nt) {
        const int col = n0 + wc * 64 + nt * 16 + l15;
        float v = acc[mt][nt][r];
        if (OUT_F32_BIAS) {
          Cf[(size_t)row * N + col] = v + bias[col];
        } else {
          Cb[(size_t)row * N + col] = f2bf(v);
        }
      }
    }
  }
}

// ---------------- 256^2 8-phase counted-vmcnt GEMM (QKV) -------------------
__global__ __launch_bounds__(512, 1) void gemm_bt8_qkv(
    const u16* __restrict__ A, const u16* __restrict__ Bm,
    u16* __restrict__ Cb, int M, int N, int K) {
  extern __shared__ u16 sm[];

  const int tid = threadIdx.x;
  const int lane = tid & 63, wid = tid >> 6;
  const int wr = wid >> 2, wc = wid & 3;
  const int l15 = lane & 15, lg = lane >> 4;
  const int xr = ((l15 >> 2) & 1) << 4;

  const int nwg = gridDim.x * gridDim.y;
  const int lin = blockIdx.y * gridDim.x + blockIdx.x;
  const int swz = (lin & 7) * (nwg >> 3) + (lin >> 3);
  const int bx = swz % gridDim.x, by = swz / gridDim.x;
  const int m0 = by * 256, n0 = bx * 256;

  const int srow = tid >> 3;
  const int kxs = ((tid & 7) * 8) ^ (((tid >> 5) & 1) << 4);
  const u16* gA = A + (size_t)(m0 + srow) * K + kxs;
  const u16* gB = Bm + (size_t)(n0 + srow) * K + kxs;

#define STG(op_, h_, tk_, c_)                                                   \
  {                                                                             \
    const u16* g_ = ((op_) ? gB : gA) + (size_t)((h_) * 128) * K + (size_t)(tk_) * 64; \
    u16* d_ = sm + (c_) * 32768 + (op_) * 16384 + (h_) * 8192 + tid * 8;        \
    async_copy16(d_, g_);                                                       \
    async_copy16(d_ + 4096, g_ + (size_t)64 * K);                               \
  }
#define LDA_(mt_, kk_, c_)                                                      \
  (*reinterpret_cast<const bf16x8*>(sm + (c_) * 32768 + wr * 8192 +             \
      ((mt_) * 16 + l15) * 64 + (((kk_) * 32 + lg * 8) ^ xr)))
#define LDB_(nt_, kk_, c_)                                                      \
  (*reinterpret_cast<const bf16x8*>(sm + (c_) * 32768 + 16384 + (wc >> 1) * 8192 + \
      ((wc & 1) * 64 + (nt_) * 16 + l15) * 64 + (((kk_) * 32 + lg * 8) ^ xr)))

  f32x4 acc[8][4];
#pragma unroll
  for (int i = 0; i < 8; i++)
#pragma unroll
    for (int j = 0; j < 4; j++) acc[i][j] = (f32x4){0.f, 0.f, 0.f, 0.f};

  const int NT = K >> 6;

  STG(0, 0, 0, 0) STG(0, 1, 0, 0) STG(1, 0, 0, 0) STG(1, 1, 0, 0)
  STG(0, 0, 1, 1) STG(0, 1, 1, 1)
  asm volatile("s_waitcnt vmcnt(4)" ::: "memory");
  __builtin_amdgcn_sched_barrier(0);
  __builtin_amdgcn_s_barrier();

  for (int t = 0; t < NT; ++t) {
    const int c = t & 1;
    bf16x8 a03[4][2], a47[4][2], b01[2][2], b23[2][2];
#pragma unroll
    for (int mt = 0; mt < 4; ++mt) {
      a03[mt][0] = LDA_(mt, 0, c);
      a03[mt][1] = LDA_(mt, 1, c);
    }
#pragma unroll
    for (int nt = 0; nt < 2; ++nt) {
      b01[nt][0] = LDB_(nt, 0, c);
      b01[nt][1] = LDB_(nt, 1, c);
    }
    if (t + 1 < NT) STG(1, 0, t + 1, c ^ 1)
    __builtin_amdgcn_s_barrier();
    asm volatile("s_waitcnt lgkmcnt(0)" ::: "memory");
    __builtin_amdgcn_sched_barrier(0);
    __builtin_amdgcn_s_setprio(1);
#pragma unroll
    for (int mt = 0; mt < 4; ++mt)
#pragma unroll
      for (int nt = 0; nt < 2; ++nt)
#pragma unroll
        for (int kk = 0; kk < 2; ++kk)
          acc[mt][nt] = __builtin_amdgcn_mfma_f32_16x16x32_bf16(
              a03[mt][kk], b01[nt][kk], acc[mt][nt], 0, 0, 0);
    __builtin_amdgcn_s_setprio(0);
    __builtin_amdgcn_s_barrier();
#pragma unroll
    for (int mt = 0; mt < 4; ++mt) {
      a47[mt][0] = LDA_(mt + 4, 0, c);
      a47[mt][1] = LDA_(mt + 4, 1, c);
    }
    if (t + 1 < NT) STG(1, 1, t + 1, c ^ 1)
    __builtin_amdgcn_s_barrier();
    asm volatile("s_waitcnt lgkmcnt(0)" ::: "memory");
    __builtin_amdgcn_sched_barrier(0);
    __builtin_amdgcn_s_setprio(1);
#pragma unroll
    for (int mt = 0; mt < 4; ++mt)
#pragma unroll
      for (int nt = 0; nt < 2; ++nt)
#pragma unroll
        for (int kk = 0; kk < 2; ++kk)
          acc[mt + 4][nt] = __builtin_amdgcn_mfma_f32_16x16x32_bf16(
              a47[mt][kk], b01[nt][kk], acc[mt + 4][nt], 0, 0, 0);
    __builtin_amdgcn_s_setprio(0);
    __builtin_amdgcn_s_barrier();
#pragma unroll
    for (int nt = 0; nt < 2; ++nt) {
      b23[nt][0] = LDB_(nt + 2, 0, c);
      b23[nt][1] = LDB_(nt + 2, 1, c);
    }
    if (t + 2 < NT) STG(0, 0, t + 2, c)
    __builtin_amdgcn_s_barrier();
    asm volatile("s_waitcnt lgkmcnt(0)" ::: "memory");
    __builtin_amdgcn_sched_barrier(0);
    __builtin_amdgcn_s_setprio(1);
#pragma unroll
    for (int mt = 0; mt < 4; ++mt)
#pragma unroll
      for (int nt = 0; nt < 2; ++nt)
#pragma unroll
        for (int kk = 0; kk < 2; ++kk)
          acc[mt][nt + 2] = __builtin_amdgcn_mfma_f32_16x16x32_bf16(
              a03[mt][kk], b23[nt][kk], acc[mt][nt + 2], 0, 0, 0);
    __builtin_amdgcn_s_setprio(0);
    __builtin_amdgcn_s_barrier();
    if (t + 2 < NT) STG(0, 1, t + 2, c)
    __builtin_amdgcn_s_barrier();
    __builtin_amdgcn_s_setprio(1);
#pragma unroll
    for (int mt = 0; mt < 4; ++mt)
#pragma unroll
      for (int nt = 0; nt < 2; ++nt)
#pragma unroll
        for (int kk = 0; kk < 2; ++kk)
          acc[mt + 4][nt + 2] = __builtin_amdgcn_mfma_f32_16x16x32_bf16(
              a47[mt][kk], b23[nt][kk], acc[mt + 4][nt + 2], 0, 0, 0);
    __builtin_amdgcn_s_setprio(0);
    if (t + 1 < NT) {
      if (t + 2 < NT) {
        asm volatile("s_waitcnt vmcnt(4)" ::: "memory");
      } else {
        asm volatile("s_waitcnt vmcnt(0)" ::: "memory");
      }
      __builtin_amdgcn_sched_barrier(0);
    }
    __builtin_amdgcn_s_barrier();
  }

  const float qsc = (n0 < D_DIM) ? ATT_C : 1.0f;
#pragma unroll
  for (int mt = 0; mt < 8; ++mt) {
#pragma unroll
    for (int r = 0; r < 4; ++r) {
      const int row = m0 + wr * 128 + mt * 16 + lg * 4 + r;
#pragma unroll
      for (int nt = 0; nt < 4; ++nt) {
        const int col = n0 + wc * 64 + nt * 16 + l15;
        Cb[(size_t)row * N + col] = f2bf(acc[mt][nt][r] * qsc);
      }
    }
  }
#undef STG
#undef LDA_
#undef LDB_
}

// ---------------- causal flash attention (R11 best-known) -------------------
#define VF_STRIDE 24
#define VF_FRAG (32 * VF_STRIDE)

__device__ __forceinline__ void process32(
    const bf16x8 (&qf)[4], f32x16 (&o)[2], f32x16& lacc,
    int q0w, int kv0, int l31, int hi, bool needMask, const bf16x8 onesf,
    const u16* __restrict__ Ks, const u16* __restrict__ Vf) {
  f32x16 s[2];
#pragma unroll
  for (int kb = 0; kb < 2; ++kb)
#pragma unroll
    for (int r = 0; r < 16; ++r) s[kb][r] = 0.f;

  __builtin_amdgcn_s_setprio(1);
#pragma unroll
  for (int kb = 0; kb < 2; ++kb) {
#pragma unroll
    for (int ks = 0; ks < 4; ++ks) {
      const int row = kb * 32 + l31;
      bf16x8 kf = *reinterpret_cast<const bf16x8*>(
          &Ks[row * 64 + ((((ks << 1) | hi)) ^ (l31 & 7)) * 8]);
      s[kb] = __builtin_amdgcn_mfma_f32_32x32x16_bf16(kf, qf[ks], s[kb], 0, 0, 0);
    }
  }
  __builtin_amdgcn_s_setprio(0);

  if (needMask) {
    const int q = q0w + l31;
#pragma unroll
    for (int kb = 0; kb < 2; ++kb)
#pragma unroll
      for (int r = 0; r < 16; ++r) {
        const int kv = kv0 + kb * 32 + (r & 3) + ((r >> 2) << 3) + (hi << 2);
        if (kv > q) s[kb][r] = -1e30f;
      }
  }
#pragma unroll
  for (int kb = 0; kb < 2; ++kb)
#pragma unroll
    for (int r = 0; r < 16; ++r)
      s[kb][r] = __builtin_amdgcn_exp2f(s[kb][r]);

  union Frag { unsigned u[4]; bf16x8 v; };
  Frag pf[4];
#pragma unroll
  for (int kb = 0; kb < 2; ++kb)
#pragma unroll
    for (int g = 0; g < 2; ++g) {
#pragma unroll
      for (int t2 = 0; t2 < 2; ++t2) {
        unsigned x, y;
        asm("v_cvt_pk_bf16_f32 %0, %1, %2"
            : "=v"(x) : "v"(s[kb][g * 8 + t2 * 2]), "v"(s[kb][g * 8 + t2 * 2 + 1]));
        asm("v_cvt_pk_bf16_f32 %0, %1, %2"
            : "=v"(y) : "v"(s[kb][g * 8 + t2 * 2 + 4]), "v"(s[kb][g * 8 + t2 * 2 + 5]));
        asm("v_permlane32_swap_b32 %0, %1" : "+v"(x), "+v"(y));
        pf[kb * 2 + g].u[t2] = x;
        pf[kb * 2 + g].u[t2 + 2] = y;
      }
    }

  __builtin_amdgcn_s_setprio(1);
#pragma unroll
  for (int ks = 0; ks < 4; ++ks) {
    lacc = __builtin_amdgcn_mfma_f32_32x32x16_bf16(onesf, pf[ks].v, lacc, 0, 0, 0);
#pragma unroll
    for (int db = 0; db < 2; ++db) {
      bf16x8 vf = *reinterpret_cast<const bf16x8*>(
          &Vf[(ks * 2 + db) * VF_FRAG + l31 * VF_STRIDE + hi * 8]);
      o[db] = __builtin_amdgcn_mfma_f32_32x32x16_bf16(vf, pf[ks].v, o[db], 0, 0, 0);
    }
  }
  __builtin_amdgcn_s_setprio(0);
}

__global__ __launch_bounds__(256, 2) void attn_kernel(
    const u16* __restrict__ qkv, u16* __restrict__ aout) {
  __shared__ __attribute__((aligned(16))) u16 Ks[128 * 64];
  __shared__ __attribute__((aligned(16))) u16 Vf[16 * VF_FRAG];

  const int tid = threadIdx.x;
  const int lane = tid & 63, w = tid >> 6;
  const int l31 = lane & 31, hi = lane >> 5;

  const int nwg = gridDim.x * gridDim.y;          // 512
  const int lin = blockIdx.y * gridDim.x + blockIdx.x;
  const int swz = (lin & 7) * (nwg >> 3) + (lin >> 3);
  const int px = swz % gridDim.x;
  const int bh = swz / gridDim.x;
  const int b = bh >> 4, h = bh & 15;
  const int qtA = px, qtB = 15 - px;
  const int q0A = qtA * 128 + w * 32, q0B = qtB * 128 + w * 32;

  bf16x8 qfA[4], qfB[4];
  {
    const u16* pA = qkv + ((size_t)(q0A + l31) * B_DIM + b) * QKV_N + h * HD + hi * 8;
    const u16* pB = qkv + ((size_t)(q0B + l31) * B_DIM + b) * QKV_N + h * HD + hi * 8;
#pragma unroll
    for (int ks = 0; ks < 4; ++ks) {
      qfA[ks] = *reinterpret_cast<const bf16x8*>(pA + ks * 16);
      qfB[ks] = *reinterpret_cast<const bf16x8*>(pB + ks * 16);
    }
  }

  bf16x8 onesf;
  {
    union { u16 u[8]; bf16x8 v; } ou;
#pragma unroll
    for (int i = 0; i < 8; ++i) ou.u[i] = 0x3F80;
    onesf = ou.v;
  }

  f32x16 oA[2], oB[2], laccA, laccB;
#pragma unroll
  for (int r = 0; r < 16; ++r) { laccA[r] = 0.f; laccB[r] = 0.f; }
#pragma unroll
  for (int db = 0; db < 2; ++db)
#pragma unroll
    for (int r = 0; r < 16; ++r) { oA[db][r] = 0.f; oB[db][r] = 0.f; }

  const int srow = tid >> 3;
  const int scol = (tid & 7) * 8;
  const int csw = (tid & 7) ^ (srow & 7);

  for (int kt2 = 0; kt2 <= qtB; ++kt2) {
    const int base = kt2 * 128;
#pragma unroll
    for (int p = 0; p < 4; ++p) {
      const u16* gK = qkv + ((size_t)(base + p * 32 + srow) * B_DIM + b) * QKV_N +
                      D_DIM + h * HD + csw * 8;
      async_copy16(Ks + tid * 8 + p * 2048, gK);
    }
    u16x8 vv[4];
#pragma unroll
    for (int p = 0; p < 4; ++p) {
      const u16* gV = qkv + ((size_t)(base + p * 32 + srow) * B_DIM + b) * QKV_N +
                      2 * D_DIM + h * HD + scol;
      vv[p] = *reinterpret_cast<const u16x8*>(gV);
    }
#pragma unroll
    for (int p = 0; p < 4; ++p) {
      const int kvl = p * 32 + srow;
      const int fb = (kvl >> 4) * 2;
      const int e16 = kvl & 15;
#pragma unroll
      for (int jj = 0; jj < 8; ++jj) {
        const int j = (jj + srow) & 7;
        const int d = scol + j;
        Vf[(fb + (d >> 5)) * VF_FRAG + (d & 31) * VF_STRIDE + e16] = vv[p][j];
      }
    }
    __syncthreads();

#pragma unroll
    for (int half = 0; half < 2; ++half) {
      const int kv0 = base + half * 64;
      const u16* Kh = Ks + half * (64 * 64);
      const u16* Vh = Vf + half * 8 * VF_FRAG;
      if (kv0 <= q0A + 31)
        process32(qfA, oA, laccA, q0A, kv0, l31, hi, kv0 + 63 > q0A, onesf, Kh, Vh);
      if (kv0 <= q0B + 31)
        process32(qfB, oB, laccB, q0B, kv0, l31, hi, kv0 + 63 > q0B, onesf, Kh, Vh);
    }
    __syncthreads();
  }

#pragma unroll
  for (int t = 0; t < 2; ++t) {
    const float inv = 1.0f / (t == 0 ? laccA[0] : laccB[0]);
    const int q0w = t == 0 ? q0A : q0B;
    f32x16* o = t == 0 ? oA : oB;
    u16* orow = aout + ((size_t)(q0w + l31) * B_DIM + b) * D_DIM + h * HD;
#pragma unroll
    for (int db = 0; db < 2; ++db)
#pragma unroll
      for (int rq = 0; rq < 4; ++rq) {
        u16x4 o4;
#pragma unroll
        for (int e = 0; e < 4; ++e) o4[e] = f2bf(o[db][rq * 4 + e] * inv);
        *reinterpret_cast<u16x4*>(orow + db * 32 + rq * 8 + hi * 4) = o4;
      }
  }
}

// ---------------- launch ----------------
extern "C" void kernel_launch(void* const* d_in, const int* in_sizes, int n_in,
                              void* d_out, int out_size, void* d_ws, size_t ws_size,
                              hipStream_t stream) {
  (void)in_sizes; (void)n_in; (void)out_size; (void)ws_size;
  const float* x = (const float*)d_in[0];
  const float* Wqkv = (const float*)d_in[1];
  const float* Wout = (const float*)d_in[2];
  const float* bout = (const float*)d_in[3];
  float* out = (float*)d_out;

  u16* xb = (u16*)d_ws;                               // [8192][1024]
  u16* wqkvb = xb + (size_t)MROWS * D_DIM;            // [3072][1024]
  u16* woutb = wqkvb + (size_t)QKV_N * D_DIM;         // [1024][1024]
  u16* qkv = woutb + (size_t)D_DIM * D_DIM;           // [8192][3072]
  u16* aout = qkv + (size_t)MROWS * QKV_N;            // [8192][1024]

  {
    const int n0 = MROWS * D_DIM;
    const int n01 = n0 + QKV_N * D_DIM;
    const int ntot = n01 + D_DIM * D_DIM;
    const int n4 = ntot / 4;
    cast3_f32_bf16<<<(n4 + 255) / 256, 256, 0, stream>>>(
        x, Wqkv, Wout, xb, n0, n01, n4);
  }

  hipFuncSetAttribute((const void*)gemm_bt8_qkv,
                      hipFuncAttributeMaxDynamicSharedMemorySize, 131072);
  gemm_bt8_qkv<<<dim3(QKV_N / 256, MROWS / 256), 512, 131072, stream>>>(
      xb, wqkvb, qkv, MROWS, QKV_N, D_DIM);

  attn_kernel<<<dim3(8, B_DIM * H_NUM), 256, 0, stream>>>(qkv, aout);

  gemm_bt<1><<<dim3(D_DIM / 128, MROWS / 128), 256, 0, stream>>>(
      aout, woutb, nullptr, out, bout, MROWS, D_DIM, D_DIM);
}

// Round 18
// 182.747 us; speedup vs baseline: 1.1387x; 1.0355x over previous
//
#include <hip/hip_runtime.h>
#include <stdint.h>

// Problem constants
#define T_DIM 2048
#define B_DIM 4
#define D_DIM 1024
#define H_NUM 16
#define HD 64
#define MROWS (T_DIM * B_DIM)     // 8192 flattened (t*B+b) rows
#define QKV_N (3 * D_DIM)         // 3072
// softmax in log2 domain: Q pre-scaled by 1/sqrt(64)*log2(e) in the QKV GEMM
#define ATT_C 0.18033688011112042f

typedef unsigned short u16;
typedef __bf16 bf16x8 __attribute__((ext_vector_type(8)));
typedef float f32x4 __attribute__((ext_vector_type(4)));
typedef float f32x16 __attribute__((ext_vector_type(16)));
typedef u16 u16x4 __attribute__((ext_vector_type(4)));
typedef u16 u16x8 __attribute__((ext_vector_type(8)));

__device__ __forceinline__ u16 f2bf(float f) {
  union { float f; unsigned u; } v; v.f = f;
  unsigned r = v.u + 0x7fffu + ((v.u >> 16) & 1u);
  return (u16)(r >> 16);
}

__device__ __forceinline__ void async_copy16(void* lds, const void* g) {
  __builtin_amdgcn_global_load_lds((__attribute__((address_space(1))) void*)(g),
                                   (__attribute__((address_space(3))) void*)(lds),
                                   16, 0, 0);
}

// ---------------- fused fp32 -> bf16 cast (3 inputs, contiguous dst) -------
__global__ __launch_bounds__(256) void cast3_f32_bf16(
    const float* __restrict__ s0, const float* __restrict__ s1,
    const float* __restrict__ s2, u16* __restrict__ dst,
    int n0, int n01, int ntot4) {
  int i = blockIdx.x * 256 + threadIdx.x;
  if (i >= ntot4) return;
  int e = i * 4;
  const float* s; int off;
  if (e < n0) { s = s0; off = 0; }
  else if (e < n01) { s = s1; off = n0; }
  else { s = s2; off = n01; }
  float4 v = *reinterpret_cast<const float4*>(s + (e - off));
  u16x4 o = {f2bf(v.x), f2bf(v.y), f2bf(v.z), f2bf(v.w)};
  *reinterpret_cast<u16x4*>(dst + e) = o;
}

// ---------------- 128^2 m97 GEMM (kept for out-projection) ----------------
template <int OUT_F32_BIAS>
__global__ __launch_bounds__(256) void gemm_bt(
    const u16* __restrict__ A, const u16* __restrict__ Bm,
    u16* __restrict__ Cb, float* __restrict__ Cf, const float* __restrict__ bias,
    int M, int N, int K) {
  __shared__ __attribute__((aligned(16))) u16 As[128 * 64];
  __shared__ __attribute__((aligned(16))) u16 Bs[128 * 64];

  const int tid = threadIdx.x;
  const int lane = tid & 63, wid = tid >> 6;
  const int l15 = lane & 15, lg = lane >> 4;
  const int wr = wid >> 1, wc = wid & 1;
  const int m0 = blockIdx.y * 128, n0 = blockIdx.x * 128;

  f32x4 acc[4][4];
#pragma unroll
  for (int i = 0; i < 4; i++)
#pragma unroll
    for (int j = 0; j < 4; j++) acc[i][j] = (f32x4){0.f, 0.f, 0.f, 0.f};

  const int srow = tid >> 3;
  const int scol = (tid & 7) * 8;
  const u16* gA = A + (size_t)(m0 + srow) * K + scol;
  const u16* gB = Bm + (size_t)(n0 + srow) * K + scol;
  u16* lA = As + tid * 8;
  u16* lB = Bs + tid * 8;

  const int KT = K >> 6;
  for (int kt = 0; kt < KT; ++kt) {
    const int kofs = kt * 64;
#pragma unroll
    for (int p = 0; p < 4; ++p) {
      async_copy16(lA + p * 256 * 8, gA + (size_t)(p * 32) * K + kofs);
      async_copy16(lB + p * 256 * 8, gB + (size_t)(p * 32) * K + kofs);
    }
    __syncthreads();
#pragma unroll
    for (int kk = 0; kk < 2; ++kk) {
      bf16x8 af[4], bfr[4];
#pragma unroll
      for (int mt = 0; mt < 4; ++mt)
        af[mt] = *reinterpret_cast<const bf16x8*>(
            &As[(wr * 64 + mt * 16 + l15) * 64 + kk * 32 + lg * 8]);
#pragma unroll
      for (int nt = 0; nt < 4; ++nt)
        bfr[nt] = *reinterpret_cast<const bf16x8*>(
            &Bs[(wc * 64 + nt * 16 + l15) * 64 + kk * 32 + lg * 8]);
#pragma unroll
      for (int mt = 0; mt < 4; ++mt)
#pragma unroll
        for (int nt = 0; nt < 4; ++nt)
          acc[mt][nt] = __builtin_amdgcn_mfma_f32_16x16x32_bf16(
              af[mt], bfr[nt], acc[mt][nt], 0, 0, 0);
    }
    __syncthreads();
  }

#pragma unroll
  for (int mt = 0; mt < 4; ++mt) {
#pragma unroll
    for (int r = 0; r < 4; ++r) {
      const int row = m0 + wr * 64 + mt * 16 + lg * 4 + r;
#pragma unroll
      for (int nt = 0; nt < 4; ++nt) {
        const int col = n0 + wc * 64 + nt * 16 + l15;
        float v = acc[mt][nt][r];
        if (OUT_F32_BIAS) {
          Cf[(size_t)row * N + col] = v + bias[col];
        } else {
          Cb[(size_t)row * N + col] = f2bf(v);
        }
      }
    }
  }
}

// ------- 128x256 4-phase counted-vmcnt GEMM (QKV; 768 blocks = 3.0 rounds) --
// C[M][N] = A[M][K]*B[N][K]^T, bf16 out, Q cols (< D_DIM) scaled by ATT_C.
// 512 thr = 8 waves (2M x 4N), per-wave C = 64x64, acc[4][4]. BK=64.
// LDS per buffer: A 128x64 (16KB) + B 256x64 (32KB) = 48KB; x2 = 96KB.
// K-tile t -> buf t&1 (A and B). Per tile, 2 compute phases:
//  p1: read A03(8)+B01(4); stage B(t+1)->buf^1; barrier; 16 MFMA; barrier.
//  p2: read B23(4); stage A(t+2)->buf (A(t) dead after p1); barrier;
//      16 MFMA; vmcnt(2) [drains B(t+1), leaves A(t+2)]; barrier.
// st_16x32 swizzle on stage-source and ds_read (row bit2 XOR col bit4).
__global__ __launch_bounds__(512, 1) void gemm_bt8b_qkv(
    const u16* __restrict__ A, const u16* __restrict__ Bm,
    u16* __restrict__ Cb, int M, int N, int K) {
  extern __shared__ u16 sm[];   // [c][A 8192 u16][B 16384 u16], c stride 24576

  const int tid = threadIdx.x;
  const int lane = tid & 63, wid = tid >> 6;
  const int wr = wid >> 2, wc = wid & 3;        // 2M x 4N
  const int l15 = lane & 15, lg = lane >> 4;
  const int xr = ((l15 >> 2) & 1) << 4;         // read-side swizzle bit

  // XCD swizzle (768 % 8 == 0)
  const int nwg = gridDim.x * gridDim.y;
  const int lin = blockIdx.y * gridDim.x + blockIdx.x;
  const int swz = (lin & 7) * (nwg >> 3) + (lin >> 3);
  const int bx = swz % gridDim.x, by = swz / gridDim.x;
  const int m0 = by * 128, n0 = bx * 256;

  // staging: thread covers row tid>>3 of a 64-row pass, 8 swizzled cols
  const int srow = tid >> 3;                          // 0..63
  const int kxs = ((tid & 7) * 8) ^ (((tid >> 5) & 1) << 4);
  const u16* gA = A + (size_t)(m0 + srow) * K + kxs;
  const u16* gB = Bm + (size_t)(n0 + srow) * K + kxs;

  // stage A (2 passes) / B (4 passes) for K-tile tk into buffer c
#define STGA(tk_, c_)                                                           \
  {                                                                             \
    _Pragma("unroll") for (int p = 0; p < 2; ++p)                               \
      async_copy16(sm + (c_) * 24576 + p * 4096 + tid * 8,                      \
                   gA + (size_t)(p * 64) * K + (size_t)(tk_) * 64);             \
  }
#define STGB(tk_, c_)                                                           \
  {                                                                             \
    _Pragma("unroll") for (int p = 0; p < 4; ++p)                               \
      async_copy16(sm + (c_) * 24576 + 8192 + p * 4096 + tid * 8,               \
                   gB + (size_t)(p * 64) * K + (size_t)(tk_) * 64);             \
  }
#define LDA_(mt_, kk_, c_)                                                      \
  (*reinterpret_cast<const bf16x8*>(sm + (c_) * 24576 +                         \
      (wr * 64 + (mt_) * 16 + l15) * 64 + (((kk_) * 32 + lg * 8) ^ xr)))
#define LDB_(nt_, kk_, c_)                                                      \
  (*reinterpret_cast<const bf16x8*>(sm + (c_) * 24576 + 8192 +                  \
      (wc * 64 + (nt_) * 16 + l15) * 64 + (((kk_) * 32 + lg * 8) ^ xr)))

  f32x4 acc[4][4];
#pragma unroll
  for (int i = 0; i < 4; i++)
#pragma unroll
    for (int j = 0; j < 4; j++) acc[i][j] = (f32x4){0.f, 0.f, 0.f, 0.f};

  const int NT = K >> 6;   // 16

  // prologue: A(0),B(0) -> buf0 [6 loads]; A(1) -> buf1 [2 loads];
  // wait all but A(1) (vmcnt(2)).
  STGA(0, 0) STGB(0, 0) STGA(1, 1)
  asm volatile("s_waitcnt vmcnt(2)" ::: "memory");
  __builtin_amdgcn_sched_barrier(0);
  __builtin_amdgcn_s_barrier();

  for (int t = 0; t < NT; ++t) {
    const int c = t & 1;
    bf16x8 a03[4][2], b01[2][2], b23[2][2];
    // ---- p1: read A03(8) + B01(4); stage B(t+1) -> c^1
#pragma unroll
    for (int mt = 0; mt < 4; ++mt) {
      a03[mt][0] = LDA_(mt, 0, c);
      a03[mt][1] = LDA_(mt, 1, c);
    }
#pragma unroll
    for (int nt = 0; nt < 2; ++nt) {
      b01[nt][0] = LDB_(nt, 0, c);
      b01[nt][1] = LDB_(nt, 1, c);
    }
    if (t + 1 < NT) STGB(t + 1, c ^ 1)
    __builtin_amdgcn_s_barrier();
    asm volatile("s_waitcnt lgkmcnt(0)" ::: "memory");
    __builtin_amdgcn_sched_barrier(0);
    __builtin_amdgcn_s_setprio(1);
#pragma unroll
    for (int mt = 0; mt < 4; ++mt)
#pragma unroll
      for (int nt = 0; nt < 2; ++nt)
#pragma unroll
        for (int kk = 0; kk < 2; ++kk)
          acc[mt][nt] = __builtin_amdgcn_mfma_f32_16x16x32_bf16(
              a03[mt][kk], b01[nt][kk], acc[mt][nt], 0, 0, 0);
    __builtin_amdgcn_s_setprio(0);
    __builtin_amdgcn_s_barrier();
    // ---- p2: read B23(4); stage A(t+2) -> c (A(t) dead since p1)
#pragma unroll
    for (int nt = 0; nt < 2; ++nt) {
      b23[nt][0] = LDB_(nt + 2, 0, c);
      b23[nt][1] = LDB_(nt + 2, 1, c);
    }
    if (t + 2 < NT) STGA(t + 2, c)
    __builtin_amdgcn_s_barrier();
    asm volatile("s_waitcnt lgkmcnt(0)" ::: "memory");
    __builtin_amdgcn_sched_barrier(0);
    __builtin_amdgcn_s_setprio(1);
#pragma unroll
    for (int mt = 0; mt < 4; ++mt)
#pragma unroll
      for (int nt = 0; nt < 2; ++nt)
#pragma unroll
        for (int kk = 0; kk < 2; ++kk)
          acc[mt][nt + 2] = __builtin_amdgcn_mfma_f32_16x16x32_bf16(
              a03[mt][kk], b23[nt][kk], acc[mt][nt + 2], 0, 0, 0);
    __builtin_amdgcn_s_setprio(0);
    // counted vmcnt: drain B(t+1) (and older A(t+1)), keep A(t+2) in flight
    if (t + 1 < NT) {
      if (t + 2 < NT) {
        asm volatile("s_waitcnt vmcnt(2)" ::: "memory");
      } else {
        asm volatile("s_waitcnt vmcnt(0)" ::: "memory");
      }
      __builtin_amdgcn_sched_barrier(0);
    }
    __builtin_amdgcn_s_barrier();
  }

  // epilogue: bf16 C write; Q block (n0 < D_DIM) pre-scaled by ATT_C
  const float qsc = (n0 < D_DIM) ? ATT_C : 1.0f;
#pragma unroll
  for (int mt = 0; mt < 4; ++mt) {
#pragma unroll
    for (int r = 0; r < 4; ++r) {
      const int row = m0 + wr * 64 + mt * 16 + lg * 4 + r;
#pragma unroll
      for (int nt = 0; nt < 4; ++nt) {
        const int col = n0 + wc * 64 + nt * 16 + l15;
        Cb[(size_t)row * N + col] = f2bf(acc[mt][nt][r] * qsc);
      }
    }
  }
#undef STGA
#undef STGB
#undef LDA_
#undef LDB_
}

// ---------------- causal flash attention (R11 best-known, unchanged) --------
#define VF_STRIDE 24
#define VF_FRAG (32 * VF_STRIDE)

__device__ __forceinline__ void process32(
    const bf16x8 (&qf)[4], f32x16 (&o)[2], f32x16& lacc,
    int q0w, int kv0, int l31, int hi, bool needMask, const bf16x8 onesf,
    const u16* __restrict__ Ks, const u16* __restrict__ Vf) {
  f32x16 s[2];
#pragma unroll
  for (int kb = 0; kb < 2; ++kb)
#pragma unroll
    for (int r = 0; r < 16; ++r) s[kb][r] = 0.f;

  __builtin_amdgcn_s_setprio(1);
#pragma unroll
  for (int kb = 0; kb < 2; ++kb) {
#pragma unroll
    for (int ks = 0; ks < 4; ++ks) {
      const int row = kb * 32 + l31;
      bf16x8 kf = *reinterpret_cast<const bf16x8*>(
          &Ks[row * 64 + ((((ks << 1) | hi)) ^ (l31 & 7)) * 8]);
      s[kb] = __builtin_amdgcn_mfma_f32_32x32x16_bf16(kf, qf[ks], s[kb], 0, 0, 0);
    }
  }
  __builtin_amdgcn_s_setprio(0);

  if (needMask) {
    const int q = q0w + l31;
#pragma unroll
    for (int kb = 0; kb < 2; ++kb)
#pragma unroll
      for (int r = 0; r < 16; ++r) {
        const int kv = kv0 + kb * 32 + (r & 3) + ((r >> 2) << 3) + (hi << 2);
        if (kv > q) s[kb][r] = -1e30f;
      }
  }
#pragma unroll
  for (int kb = 0; kb < 2; ++kb)
#pragma unroll
    for (int r = 0; r < 16; ++r)
      s[kb][r] = __builtin_amdgcn_exp2f(s[kb][r]);

  union Frag { unsigned u[4]; bf16x8 v; };
  Frag pf[4];
#pragma unroll
  for (int kb = 0; kb < 2; ++kb)
#pragma unroll
    for (int g = 0; g < 2; ++g) {
#pragma unroll
      for (int t2 = 0; t2 < 2; ++t2) {
        unsigned x, y;
        asm("v_cvt_pk_bf16_f32 %0, %1, %2"
            : "=v"(x) : "v"(s[kb][g * 8 + t2 * 2]), "v"(s[kb][g * 8 + t2 * 2 + 1]));
        asm("v_cvt_pk_bf16_f32 %0, %1, %2"
            : "=v"(y) : "v"(s[kb][g * 8 + t2 * 2 + 4]), "v"(s[kb][g * 8 + t2 * 2 + 5]));
        asm("v_permlane32_swap_b32 %0, %1" : "+v"(x), "+v"(y));
        pf[kb * 2 + g].u[t2] = x;
        pf[kb * 2 + g].u[t2 + 2] = y;
      }
    }

  __builtin_amdgcn_s_setprio(1);
#pragma unroll
  for (int ks = 0; ks < 4; ++ks) {
    lacc = __builtin_amdgcn_mfma_f32_32x32x16_bf16(onesf, pf[ks].v, lacc, 0, 0, 0);
#pragma unroll
    for (int db = 0; db < 2; ++db) {
      bf16x8 vf = *reinterpret_cast<const bf16x8*>(
          &Vf[(ks * 2 + db) * VF_FRAG + l31 * VF_STRIDE + hi * 8]);
      o[db] = __builtin_amdgcn_mfma_f32_32x32x16_bf16(vf, pf[ks].v, o[db], 0, 0, 0);
    }
  }
  __builtin_amdgcn_s_setprio(0);
}

__global__ __launch_bounds__(256, 2) void attn_kernel(
    const u16* __restrict__ qkv, u16* __restrict__ aout) {
  __shared__ __attribute__((aligned(16))) u16 Ks[128 * 64];
  __shared__ __attribute__((aligned(16))) u16 Vf[16 * VF_FRAG];

  const int tid = threadIdx.x;
  const int lane = tid & 63, w = tid >> 6;
  const int l31 = lane & 31, hi = lane >> 5;

  const int nwg = gridDim.x * gridDim.y;          // 512
  const int lin = blockIdx.y * gridDim.x + blockIdx.x;
  const int swz = (lin & 7) * (nwg >> 3) + (lin >> 3);
  const int px = swz % gridDim.x;
  const int bh = swz / gridDim.x;
  const int b = bh >> 4, h = bh & 15;
  const int qtA = px, qtB = 15 - px;
  const int q0A = qtA * 128 + w * 32, q0B = qtB * 128 + w * 32;

  bf16x8 qfA[4], qfB[4];
  {
    const u16* pA = qkv + ((size_t)(q0A + l31) * B_DIM + b) * QKV_N + h * HD + hi * 8;
    const u16* pB = qkv + ((size_t)(q0B + l31) * B_DIM + b) * QKV_N + h * HD + hi * 8;
#pragma unroll
    for (int ks = 0; ks < 4; ++ks) {
      qfA[ks] = *reinterpret_cast<const bf16x8*>(pA + ks * 16);
      qfB[ks] = *reinterpret_cast<const bf16x8*>(pB + ks * 16);
    }
  }

  bf16x8 onesf;
  {
    union { u16 u[8]; bf16x8 v; } ou;
#pragma unroll
    for (int i = 0; i < 8; ++i) ou.u[i] = 0x3F80;
    onesf = ou.v;
  }

  f32x16 oA[2], oB[2], laccA, laccB;
#pragma unroll
  for (int r = 0; r < 16; ++r) { laccA[r] = 0.f; laccB[r] = 0.f; }
#pragma unroll
  for (int db = 0; db < 2; ++db)
#pragma unroll
    for (int r = 0; r < 16; ++r) { oA[db][r] = 0.f; oB[db][r] = 0.f; }

  const int srow = tid >> 3;
  const int scol = (tid & 7) * 8;
  const int csw = (tid & 7) ^ (srow & 7);

  for (int kt2 = 0; kt2 <= qtB; ++kt2) {
    const int base = kt2 * 128;
#pragma unroll
    for (int p = 0; p < 4; ++p) {
      const u16* gK = qkv + ((size_t)(base + p * 32 + srow) * B_DIM + b) * QKV_N +
                      D_DIM + h * HD + csw * 8;
      async_copy16(Ks + tid * 8 + p * 2048, gK);
    }
    u16x8 vv[4];
#pragma unroll
    for (int p = 0; p < 4; ++p) {
      const u16* gV = qkv + ((size_t)(base + p * 32 + srow) * B_DIM + b) * QKV_N +
                      2 * D_DIM + h * HD + scol;
      vv[p] = *reinterpret_cast<const u16x8*>(gV);
    }
#pragma unroll
    for (int p = 0; p < 4; ++p) {
      const int kvl = p * 32 + srow;
      const int fb = (kvl >> 4) * 2;
      const int e16 = kvl & 15;
#pragma unroll
      for (int jj = 0; jj < 8; ++jj) {
        const int j = (jj + srow) & 7;
        const int d = scol + j;
        Vf[(fb + (d >> 5)) * VF_FRAG + (d & 31) * VF_STRIDE + e16] = vv[p][j];
      }
    }
    __syncthreads();

#pragma unroll
    for (int half = 0; half < 2; ++half) {
      const int kv0 = base + half * 64;
      const u16* Kh = Ks + half * (64 * 64);
      const u16* Vh = Vf + half * 8 * VF_FRAG;
      if (kv0 <= q0A + 31)
        process32(qfA, oA, laccA, q0A, kv0, l31, hi, kv0 + 63 > q0A, onesf, Kh, Vh);
      if (kv0 <= q0B + 31)
        process32(qfB, oB, laccB, q0B, kv0, l31, hi, kv0 + 63 > q0B, onesf, Kh, Vh);
    }
    __syncthreads();
  }

#pragma unroll
  for (int t = 0; t < 2; ++t) {
    const float inv = 1.0f / (t == 0 ? laccA[0] : laccB[0]);
    const int q0w = t == 0 ? q0A : q0B;
    f32x16* o = t == 0 ? oA : oB;
    u16* orow = aout + ((size_t)(q0w + l31) * B_DIM + b) * D_DIM + h * HD;
#pragma unroll
    for (int db = 0; db < 2; ++db)
#pragma unroll
      for (int rq = 0; rq < 4; ++rq) {
        u16x4 o4;
#pragma unroll
        for (int e = 0; e < 4; ++e) o4[e] = f2bf(o[db][rq * 4 + e] * inv);
        *reinterpret_cast<u16x4*>(orow + db * 32 + rq * 8 + hi * 4) = o4;
      }
  }
}

// ---------------- launch ----------------
extern "C" void kernel_launch(void* const* d_in, const int* in_sizes, int n_in,
                              void* d_out, int out_size, void* d_ws, size_t ws_size,
                              hipStream_t stream) {
  (void)in_sizes; (void)n_in; (void)out_size; (void)ws_size;
  const float* x = (const float*)d_in[0];
  const float* Wqkv = (const float*)d_in[1];
  const float* Wout = (const float*)d_in[2];
  const float* bout = (const float*)d_in[3];
  float* out = (float*)d_out;

  u16* xb = (u16*)d_ws;                               // [8192][1024]
  u16* wqkvb = xb + (size_t)MROWS * D_DIM;            // [3072][1024]
  u16* woutb = wqkvb + (size_t)QKV_N * D_DIM;         // [1024][1024]
  u16* qkv = woutb + (size_t)D_DIM * D_DIM;           // [8192][3072]
  u16* aout = qkv + (size_t)MROWS * QKV_N;            // [8192][1024]

  {
    const int n0 = MROWS * D_DIM;
    const int n01 = n0 + QKV_N * D_DIM;
    const int ntot = n01 + D_DIM * D_DIM;
    const int n4 = ntot / 4;
    cast3_f32_bf16<<<(n4 + 255) / 256, 256, 0, stream>>>(
        x, Wqkv, Wout, xb, n0, n01, n4);
  }

  // QKV GEMM: 128x256 4-phase, 96 KiB dynamic LDS, 768 blocks (3.0 rounds)
  hipFuncSetAttribute((const void*)gemm_bt8b_qkv,
                      hipFuncAttributeMaxDynamicSharedMemorySize, 98304);
  gemm_bt8b_qkv<<<dim3(QKV_N / 256, MROWS / 128), 512, 98304, stream>>>(
      xb, wqkvb, qkv, MROWS, QKV_N, D_DIM);

  attn_kernel<<<dim3(8, B_DIM * H_NUM), 256, 0, stream>>>(qkv, aout);

  gemm_bt<1><<<dim3(D_DIM / 128, MROWS / 128), 256, 0, stream>>>(
      aout, woutb, nullptr, out, bout, MROWS, D_DIM, D_DIM);
}

// Round 19
// 178.428 us; speedup vs baseline: 1.1663x; 1.0242x over previous
//
#include <hip/hip_runtime.h>
#include <stdint.h>

// Problem constants
#define T_DIM 2048
#define B_DIM 4
#define D_DIM 1024
#define H_NUM 16
#define HD 64
#define MROWS (T_DIM * B_DIM)     // 8192 flattened (t*B+b) rows
#define QKV_N (3 * D_DIM)         // 3072
// softmax in log2 domain: Q pre-scaled by 1/sqrt(64)*log2(e) in the QKV GEMM
#define ATT_C 0.18033688011112042f

typedef unsigned short u16;
typedef __bf16 bf16x8 __attribute__((ext_vector_type(8)));
typedef float f32x4 __attribute__((ext_vector_type(4)));
typedef float f32x16 __attribute__((ext_vector_type(16)));
typedef u16 u16x4 __attribute__((ext_vector_type(4)));
typedef u16 u16x8 __attribute__((ext_vector_type(8)));

__device__ __forceinline__ u16 f2bf(float f) {
  union { float f; unsigned u; } v; v.f = f;
  unsigned r = v.u + 0x7fffu + ((v.u >> 16) & 1u);
  return (u16)(r >> 16);
}

__device__ __forceinline__ void async_copy16(void* lds, const void* g) {
  __builtin_amdgcn_global_load_lds((__attribute__((address_space(1))) void*)(g),
                                   (__attribute__((address_space(3))) void*)(lds),
                                   16, 0, 0);
}

// ---------------- fused fp32 -> bf16 cast (3 inputs, contiguous dst) -------
__global__ __launch_bounds__(256) void cast3_f32_bf16(
    const float* __restrict__ s0, const float* __restrict__ s1,
    const float* __restrict__ s2, u16* __restrict__ dst,
    int n0, int n01, int ntot4) {
  int i = blockIdx.x * 256 + threadIdx.x;
  if (i >= ntot4) return;
  int e = i * 4;
  const float* s; int off;
  if (e < n0) { s = s0; off = 0; }
  else if (e < n01) { s = s1; off = n0; }
  else { s = s2; off = n01; }
  float4 v = *reinterpret_cast<const float4*>(s + (e - off));
  u16x4 o = {f2bf(v.x), f2bf(v.y), f2bf(v.z), f2bf(v.w)};
  *reinterpret_cast<u16x4*>(dst + e) = o;
}

// ------- 128x256 4-phase counted-vmcnt GEMM ---------------------------------
// C[M][N] = A[M][K]*B[N][K]^T. MODE 0: bf16 out, Q cols (< D_DIM) scaled by
// ATT_C. MODE 1: f32 out + bias.
// 512 thr = 8 waves (2M x 4N), per-wave C = 64x64, acc[4][4]. BK=64.
// LDS per buffer: A 128x64 (16KB) + B 256x64 (32KB) = 48KB; x2 = 96KB.
// K-tile t -> buf t&1. Per tile, 2 compute phases:
//  p1: read A03(8)+B01(4); stage B(t+1)->buf^1; barrier; 16 MFMA; barrier.
//  p2: read B23(4); stage A(t+2)->buf (A(t) dead after p1); barrier;
//      16 MFMA; vmcnt(2) [drains B(t+1), leaves A(t+2)]; barrier.
// st_16x32 swizzle on stage-source and ds_read (row bit2 XOR col bit4).
template <int OUT_F32_BIAS>
__global__ __launch_bounds__(512, 1) void gemm_bt8b(
    const u16* __restrict__ A, const u16* __restrict__ Bm,
    u16* __restrict__ Cb, float* __restrict__ Cf, const float* __restrict__ bias,
    int M, int N, int K) {
  extern __shared__ u16 sm[];   // [c][A 8192 u16][B 16384 u16], c stride 24576

  const int tid = threadIdx.x;
  const int lane = tid & 63, wid = tid >> 6;
  const int wr = wid >> 2, wc = wid & 3;        // 2M x 4N
  const int l15 = lane & 15, lg = lane >> 4;
  const int xr = ((l15 >> 2) & 1) << 4;         // read-side swizzle bit

  // XCD swizzle (nwg % 8 == 0)
  const int nwg = gridDim.x * gridDim.y;
  const int lin = blockIdx.y * gridDim.x + blockIdx.x;
  const int swz = (lin & 7) * (nwg >> 3) + (lin >> 3);
  const int bx = swz % gridDim.x, by = swz / gridDim.x;
  const int m0 = by * 128, n0 = bx * 256;

  const int srow = tid >> 3;                          // 0..63
  const int kxs = ((tid & 7) * 8) ^ (((tid >> 5) & 1) << 4);
  const u16* gA = A + (size_t)(m0 + srow) * K + kxs;
  const u16* gB = Bm + (size_t)(n0 + srow) * K + kxs;

#define STGA(tk_, c_)                                                           \
  {                                                                             \
    _Pragma("unroll") for (int p = 0; p < 2; ++p)                               \
      async_copy16(sm + (c_) * 24576 + p * 4096 + tid * 8,                      \
                   gA + (size_t)(p * 64) * K + (size_t)(tk_) * 64);             \
  }
#define STGB(tk_, c_)                                                           \
  {                                                                             \
    _Pragma("unroll") for (int p = 0; p < 4; ++p)                               \
      async_copy16(sm + (c_) * 24576 + 8192 + p * 4096 + tid * 8,               \
                   gB + (size_t)(p * 64) * K + (size_t)(tk_) * 64);             \
  }
#define LDA_(mt_, kk_, c_)                                                      \
  (*reinterpret_cast<const bf16x8*>(sm + (c_) * 24576 +                         \
      (wr * 64 + (mt_) * 16 + l15) * 64 + (((kk_) * 32 + lg * 8) ^ xr)))
#define LDB_(nt_, kk_, c_)                                                      \
  (*reinterpret_cast<const bf16x8*>(sm + (c_) * 24576 + 8192 +                  \
      (wc * 64 + (nt_) * 16 + l15) * 64 + (((kk_) * 32 + lg * 8) ^ xr)))

  f32x4 acc[4][4];
#pragma unroll
  for (int i = 0; i < 4; i++)
#pragma unroll
    for (int j = 0; j < 4; j++) acc[i][j] = (f32x4){0.f, 0.f, 0.f, 0.f};

  const int NT = K >> 6;   // 16

  STGA(0, 0) STGB(0, 0) STGA(1, 1)
  asm volatile("s_waitcnt vmcnt(2)" ::: "memory");
  __builtin_amdgcn_sched_barrier(0);
  __builtin_amdgcn_s_barrier();

  for (int t = 0; t < NT; ++t) {
    const int c = t & 1;
    bf16x8 a03[4][2], b01[2][2], b23[2][2];
    // ---- p1: read A03(8) + B01(4); stage B(t+1) -> c^1
#pragma unroll
    for (int mt = 0; mt < 4; ++mt) {
      a03[mt][0] = LDA_(mt, 0, c);
      a03[mt][1] = LDA_(mt, 1, c);
    }
#pragma unroll
    for (int nt = 0; nt < 2; ++nt) {
      b01[nt][0] = LDB_(nt, 0, c);
      b01[nt][1] = LDB_(nt, 1, c);
    }
    if (t + 1 < NT) STGB(t + 1, c ^ 1)
    __builtin_amdgcn_s_barrier();
    asm volatile("s_waitcnt lgkmcnt(0)" ::: "memory");
    __builtin_amdgcn_sched_barrier(0);
    __builtin_amdgcn_s_setprio(1);
#pragma unroll
    for (int mt = 0; mt < 4; ++mt)
#pragma unroll
      for (int nt = 0; nt < 2; ++nt)
#pragma unroll
        for (int kk = 0; kk < 2; ++kk)
          acc[mt][nt] = __builtin_amdgcn_mfma_f32_16x16x32_bf16(
              a03[mt][kk], b01[nt][kk], acc[mt][nt], 0, 0, 0);
    __builtin_amdgcn_s_setprio(0);
    __builtin_amdgcn_s_barrier();
    // ---- p2: read B23(4); stage A(t+2) -> c (A(t) dead since p1)
#pragma unroll
    for (int nt = 0; nt < 2; ++nt) {
      b23[nt][0] = LDB_(nt + 2, 0, c);
      b23[nt][1] = LDB_(nt + 2, 1, c);
    }
    if (t + 2 < NT) STGA(t + 2, c)
    __builtin_amdgcn_s_barrier();
    asm volatile("s_waitcnt lgkmcnt(0)" ::: "memory");
    __builtin_amdgcn_sched_barrier(0);
    __builtin_amdgcn_s_setprio(1);
#pragma unroll
    for (int mt = 0; mt < 4; ++mt)
#pragma unroll
      for (int nt = 0; nt < 2; ++nt)
#pragma unroll
        for (int kk = 0; kk < 2; ++kk)
          acc[mt][nt + 2] = __builtin_amdgcn_mfma_f32_16x16x32_bf16(
              a03[mt][kk], b23[nt][kk], acc[mt][nt + 2], 0, 0, 0);
    __builtin_amdgcn_s_setprio(0);
    if (t + 1 < NT) {
      if (t + 2 < NT) {
        asm volatile("s_waitcnt vmcnt(2)" ::: "memory");
      } else {
        asm volatile("s_waitcnt vmcnt(0)" ::: "memory");
      }
      __builtin_amdgcn_sched_barrier(0);
    }
    __builtin_amdgcn_s_barrier();
  }

  // epilogue
  const float qsc = (!OUT_F32_BIAS && n0 < D_DIM) ? ATT_C : 1.0f;
#pragma unroll
  for (int mt = 0; mt < 4; ++mt) {
#pragma unroll
    for (int r = 0; r < 4; ++r) {
      const int row = m0 + wr * 64 + mt * 16 + lg * 4 + r;
#pragma unroll
      for (int nt = 0; nt < 4; ++nt) {
        const int col = n0 + wc * 64 + nt * 16 + l15;
        if (OUT_F32_BIAS) {
          Cf[(size_t)row * N + col] = acc[mt][nt][r] + bias[col];
        } else {
          Cb[(size_t)row * N + col] = f2bf(acc[mt][nt][r] * qsc);
        }
      }
    }
  }
#undef STGA
#undef STGB
#undef LDA_
#undef LDB_
}

// ---------------- causal flash attention (R11 best-known, unchanged) --------
#define VF_STRIDE 24
#define VF_FRAG (32 * VF_STRIDE)

__device__ __forceinline__ void process32(
    const bf16x8 (&qf)[4], f32x16 (&o)[2], f32x16& lacc,
    int q0w, int kv0, int l31, int hi, bool needMask, const bf16x8 onesf,
    const u16* __restrict__ Ks, const u16* __restrict__ Vf) {
  f32x16 s[2];
#pragma unroll
  for (int kb = 0; kb < 2; ++kb)
#pragma unroll
    for (int r = 0; r < 16; ++r) s[kb][r] = 0.f;

  __builtin_amdgcn_s_setprio(1);
#pragma unroll
  for (int kb = 0; kb < 2; ++kb) {
#pragma unroll
    for (int ks = 0; ks < 4; ++ks) {
      const int row = kb * 32 + l31;
      bf16x8 kf = *reinterpret_cast<const bf16x8*>(
          &Ks[row * 64 + ((((ks << 1) | hi)) ^ (l31 & 7)) * 8]);
      s[kb] = __builtin_amdgcn_mfma_f32_32x32x16_bf16(kf, qf[ks], s[kb], 0, 0, 0);
    }
  }
  __builtin_amdgcn_s_setprio(0);

  if (needMask) {
    const int q = q0w + l31;
#pragma unroll
    for (int kb = 0; kb < 2; ++kb)
#pragma unroll
      for (int r = 0; r < 16; ++r) {
        const int kv = kv0 + kb * 32 + (r & 3) + ((r >> 2) << 3) + (hi << 2);
        if (kv > q) s[kb][r] = -1e30f;
      }
  }
#pragma unroll
  for (int kb = 0; kb < 2; ++kb)
#pragma unroll
    for (int r = 0; r < 16; ++r)
      s[kb][r] = __builtin_amdgcn_exp2f(s[kb][r]);

  union Frag { unsigned u[4]; bf16x8 v; };
  Frag pf[4];
#pragma unroll
  for (int kb = 0; kb < 2; ++kb)
#pragma unroll
    for (int g = 0; g < 2; ++g) {
#pragma unroll
      for (int t2 = 0; t2 < 2; ++t2) {
        unsigned x, y;
        asm("v_cvt_pk_bf16_f32 %0, %1, %2"
            : "=v"(x) : "v"(s[kb][g * 8 + t2 * 2]), "v"(s[kb][g * 8 + t2 * 2 + 1]));
        asm("v_cvt_pk_bf16_f32 %0, %1, %2"
            : "=v"(y) : "v"(s[kb][g * 8 + t2 * 2 + 4]), "v"(s[kb][g * 8 + t2 * 2 + 5]));
        asm("v_permlane32_swap_b32 %0, %1" : "+v"(x), "+v"(y));
        pf[kb * 2 + g].u[t2] = x;
        pf[kb * 2 + g].u[t2 + 2] = y;
      }
    }

  __builtin_amdgcn_s_setprio(1);
#pragma unroll
  for (int ks = 0; ks < 4; ++ks) {
    lacc = __builtin_amdgcn_mfma_f32_32x32x16_bf16(onesf, pf[ks].v, lacc, 0, 0, 0);
#pragma unroll
    for (int db = 0; db < 2; ++db) {
      bf16x8 vf = *reinterpret_cast<const bf16x8*>(
          &Vf[(ks * 2 + db) * VF_FRAG + l31 * VF_STRIDE + hi * 8]);
      o[db] = __builtin_amdgcn_mfma_f32_32x32x16_bf16(vf, pf[ks].v, o[db], 0, 0, 0);
    }
  }
  __builtin_amdgcn_s_setprio(0);
}

__global__ __launch_bounds__(256, 2) void attn_kernel(
    const u16* __restrict__ qkv, u16* __restrict__ aout) {
  __shared__ __attribute__((aligned(16))) u16 Ks[128 * 64];
  __shared__ __attribute__((aligned(16))) u16 Vf[16 * VF_FRAG];

  const int tid = threadIdx.x;
  const int lane = tid & 63, w = tid >> 6;
  const int l31 = lane & 31, hi = lane >> 5;

  const int nwg = gridDim.x * gridDim.y;          // 512
  const int lin = blockIdx.y * gridDim.x + blockIdx.x;
  const int swz = (lin & 7) * (nwg >> 3) + (lin >> 3);
  const int px = swz % gridDim.x;
  const int bh = swz / gridDim.x;
  const int b = bh >> 4, h = bh & 15;
  const int qtA = px, qtB = 15 - px;
  const int q0A = qtA * 128 + w * 32, q0B = qtB * 128 + w * 32;

  bf16x8 qfA[4], qfB[4];
  {
    const u16* pA = qkv + ((size_t)(q0A + l31) * B_DIM + b) * QKV_N + h * HD + hi * 8;
    const u16* pB = qkv + ((size_t)(q0B + l31) * B_DIM + b) * QKV_N + h * HD + hi * 8;
#pragma unroll
    for (int ks = 0; ks < 4; ++ks) {
      qfA[ks] = *reinterpret_cast<const bf16x8*>(pA + ks * 16);
      qfB[ks] = *reinterpret_cast<const bf16x8*>(pB + ks * 16);
    }
  }

  bf16x8 onesf;
  {
    union { u16 u[8]; bf16x8 v; } ou;
#pragma unroll
    for (int i = 0; i < 8; ++i) ou.u[i] = 0x3F80;
    onesf = ou.v;
  }

  f32x16 oA[2], oB[2], laccA, laccB;
#pragma unroll
  for (int r = 0; r < 16; ++r) { laccA[r] = 0.f; laccB[r] = 0.f; }
#pragma unroll
  for (int db = 0; db < 2; ++db)
#pragma unroll
    for (int r = 0; r < 16; ++r) { oA[db][r] = 0.f; oB[db][r] = 0.f; }

  const int srow = tid >> 3;
  const int scol = (tid & 7) * 8;
  const int csw = (tid & 7) ^ (srow & 7);

  for (int kt2 = 0; kt2 <= qtB; ++kt2) {
    const int base = kt2 * 128;
#pragma unroll
    for (int p = 0; p < 4; ++p) {
      const u16* gK = qkv + ((size_t)(base + p * 32 + srow) * B_DIM + b) * QKV_N +
                      D_DIM + h * HD + csw * 8;
      async_copy16(Ks + tid * 8 + p * 2048, gK);
    }
    u16x8 vv[4];
#pragma unroll
    for (int p = 0; p < 4; ++p) {
      const u16* gV = qkv + ((size_t)(base + p * 32 + srow) * B_DIM + b) * QKV_N +
                      2 * D_DIM + h * HD + scol;
      vv[p] = *reinterpret_cast<const u16x8*>(gV);
    }
#pragma unroll
    for (int p = 0; p < 4; ++p) {
      const int kvl = p * 32 + srow;
      const int fb = (kvl >> 4) * 2;
      const int e16 = kvl & 15;
#pragma unroll
      for (int jj = 0; jj < 8; ++jj) {
        const int j = (jj + srow) & 7;
        const int d = scol + j;
        Vf[(fb + (d >> 5)) * VF_FRAG + (d & 31) * VF_STRIDE + e16] = vv[p][j];
      }
    }
    __syncthreads();

#pragma unroll
    for (int half = 0; half < 2; ++half) {
      const int kv0 = base + half * 64;
      const u16* Kh = Ks + half * (64 * 64);
      const u16* Vh = Vf + half * 8 * VF_FRAG;
      if (kv0 <= q0A + 31)
        process32(qfA, oA, laccA, q0A, kv0, l31, hi, kv0 + 63 > q0A, onesf, Kh, Vh);
      if (kv0 <= q0B + 31)
        process32(qfB, oB, laccB, q0B, kv0, l31, hi, kv0 + 63 > q0B, onesf, Kh, Vh);
    }
    __syncthreads();
  }

#pragma unroll
  for (int t = 0; t < 2; ++t) {
    const float inv = 1.0f / (t == 0 ? laccA[0] : laccB[0]);
    const int q0w = t == 0 ? q0A : q0B;
    f32x16* o = t == 0 ? oA : oB;
    u16* orow = aout + ((size_t)(q0w + l31) * B_DIM + b) * D_DIM + h * HD;
#pragma unroll
    for (int db = 0; db < 2; ++db)
#pragma unroll
      for (int rq = 0; rq < 4; ++rq) {
        u16x4 o4;
#pragma unroll
        for (int e = 0; e < 4; ++e) o4[e] = f2bf(o[db][rq * 4 + e] * inv);
        *reinterpret_cast<u16x4*>(orow + db * 32 + rq * 8 + hi * 4) = o4;
      }
  }
}

// ---------------- launch ----------------
extern "C" void kernel_launch(void* const* d_in, const int* in_sizes, int n_in,
                              void* d_out, int out_size, void* d_ws, size_t ws_size,
                              hipStream_t stream) {
  (void)in_sizes; (void)n_in; (void)out_size; (void)ws_size;
  const float* x = (const float*)d_in[0];
  const float* Wqkv = (const float*)d_in[1];
  const float* Wout = (const float*)d_in[2];
  const float* bout = (const float*)d_in[3];
  float* out = (float*)d_out;

  u16* xb = (u16*)d_ws;                               // [8192][1024]
  u16* wqkvb = xb + (size_t)MROWS * D_DIM;            // [3072][1024]
  u16* woutb = wqkvb + (size_t)QKV_N * D_DIM;         // [1024][1024]
  u16* qkv = woutb + (size_t)D_DIM * D_DIM;           // [8192][3072]
  u16* aout = qkv + (size_t)MROWS * QKV_N;            // [8192][1024]

  {
    const int n0 = MROWS * D_DIM;
    const int n01 = n0 + QKV_N * D_DIM;
    const int ntot = n01 + D_DIM * D_DIM;
    const int n4 = ntot / 4;
    cast3_f32_bf16<<<(n4 + 255) / 256, 256, 0, stream>>>(
        x, Wqkv, Wout, xb, n0, n01, n4);
  }

  // QKV GEMM: 128x256 4-phase, 96 KiB dynamic LDS, 768 blocks (3.0 rounds)
  hipFuncSetAttribute((const void*)gemm_bt8b<0>,
                      hipFuncAttributeMaxDynamicSharedMemorySize, 98304);
  gemm_bt8b<0><<<dim3(QKV_N / 256, MROWS / 128), 512, 98304, stream>>>(
      xb, wqkvb, qkv, nullptr, nullptr, MROWS, QKV_N, D_DIM);

  attn_kernel<<<dim3(8, B_DIM * H_NUM), 256, 0, stream>>>(qkv, aout);

  // out-proj: 128x256 4-phase, 256 blocks (exactly 1.0 rounds), f32+bias out
  hipFuncSetAttribute((const void*)gemm_bt8b<1>,
                      hipFuncAttributeMaxDynamicSharedMemorySize, 98304);
  gemm_bt8b<1><<<dim3(D_DIM / 256, MROWS / 128), 512, 98304, stream>>>(
      aout, woutb, nullptr, out, bout, MROWS, D_DIM, D_DIM);
}